// Round 6
// baseline (86.848 us; speedup 1.0000x reference)
//
#include <hip/hip_runtime.h>

// Problem constants (match reference): B=64, L=2048, H=256, K=32
#define LL 2048
#define BB 64
#define HH 256
#define KK 32

#define NB  1024   // grid blocks
#define WPB 4      // waves per block

typedef __attribute__((ext_vector_type(8))) short  short8;   // 8 bf16 (4 VGPRs)
typedef __attribute__((ext_vector_type(4))) float  f32x4;

__device__ __forceinline__ float softplus_f(float x) {
    return x > 20.f ? x : __logf(1.f + __expf(x));
}
// round-to-nearest-even fp32 -> bf16
__device__ __forceinline__ unsigned f2bf(float x) {
    unsigned u = __builtin_bit_cast(unsigned, x);
    return (u + 0x7FFFu + ((u >> 16) & 1u)) >> 16;
}
__device__ __forceinline__ short8 pack_bf16x8(float4 a, float4 b) {
    union { unsigned u[4]; short8 s; } r;
    r.u[0] = f2bf(a.x) | (f2bf(a.y) << 16);
    r.u[1] = f2bf(a.z) | (f2bf(a.w) << 16);
    r.u[2] = f2bf(b.x) | (f2bf(b.y) << 16);
    r.u[3] = f2bf(b.z) | (f2bf(b.w) << 16);
    return r.s;
}

// Direct-to-fragment design: 16 flat rows per wave-tile, no LDS data staging.
// Lane l owns row (l&15), h-slice 8*(l>>4)+j per 32-wide K-chunk: exactly the
// mfma_f32_16x16x32_bf16 A-fragment. W^T fragments live in 64 VGPRs (loaded
// once). C[16][32] twice: v-rows (term2) and hidden-rows (term1).
__global__ __launch_bounds__(256, 3) void nhll_main(
    const int*   __restrict__ events,   // [B, L]
    const int*   __restrict__ lens,     // [B]
    const float* __restrict__ ttime,    // [B]
    const float* __restrict__ hidden,   // [L, B, H]
    const float* __restrict__ cell,     // [L, B, H]
    const float* __restrict__ ctarg,    // [L, B, H]
    const float* __restrict__ outp,     // [L, B, H]
    const float* __restrict__ decay,    // [L, B, H]
    const float* __restrict__ simt,     // [L, B]
    const float* __restrict__ W,        // [H, K]
    const float* __restrict__ bias,     // [K]
    float*       __restrict__ partial)  // [NB]
{
    __shared__ int   pfx[BB + 1];
    __shared__ float coef_s[BB];
    __shared__ float wacc[WPB];

    const int tid  = threadIdx.x;
    const int lane = tid & 63;
    const int q    = tid >> 6;
    const int g    = lane >> 4;     // h-octet within K-chunk
    const int m    = lane & 15;     // row / output-col index

    // ---- W^T B-fragments into registers (one-time, L2/L3-resident) ----
    short8 w0f[8], w1f[8];
#pragma unroll
    for (int c = 0; c < 8; ++c) {
        const int k0 = 32 * c + 8 * g;          // contraction index = h
        float a0[8], a1[8];
#pragma unroll
        for (int j = 0; j < 8; ++j) {
            a0[j] = W[(k0 + j) * KK + m];
            a1[j] = W[(k0 + j) * KK + 16 + m];
        }
        w0f[c] = pack_bf16x8(make_float4(a0[0], a0[1], a0[2], a0[3]),
                             make_float4(a0[4], a0[5], a0[6], a0[7]));
        w1f[c] = pack_bf16x8(make_float4(a1[0], a1[1], a1[2], a1[3]),
                             make_float4(a1[4], a1[5], a1[6], a1[7]));
    }
    const float b_lo = bias[m];
    const float b_hi = bias[16 + m];

    if (tid < BB) {                 // wave 0: scan lens -> prefix sums
        const int ln = lens[tid];
        coef_s[tid] = ttime[tid] / (float)ln;
        int s = ln;
#pragma unroll
        for (int mm = 1; mm < 64; mm <<= 1) {
            const int t = __shfl_up(s, mm, 64);
            if (lane >= mm) s += t;
        }
        pfx[tid + 1] = s;
        if (tid == 0) pfx[0] = 0;
    }
    __syncthreads();

    const int T      = pfx[BB];
    const int ntiles = (T + 15) >> 4;
    float acc = 0.f;

    for (int tile = blockIdx.x * WPB + q; tile < ntiles; tile += NB * WPB) {
        // ---- per-lane row metadata: lane handles flat row i0 + m ----
        int i = tile * 16 + m;
        const int valid = (i < T) ? 1 : 0;
        if (!valid) i = T - 1;                    // clamp; masked below
        int lo = 0, hi = BB;
#pragma unroll
        for (int s = 0; s < 6; ++s) {
            const int mid = (lo + hi) >> 1;
            if (pfx[mid] <= i) lo = mid; else hi = mid;
        }
        const int   b    = lo;
        const int   l    = i - pfx[b];
        const int   r    = l * BB + b;
        const float st   = simt[r];
        const float coef = valid ? coef_s[b] : 0.f;
        const int   e    = events[b * LL + l + 1];   // l+1 <= 2046: in-bounds

        const int base = r * HH + 8 * g;
        const float* ph = hidden + base;
        const float* pc = cell   + base;
        const float* pt = ctarg  + base;
        const float* po = outp   + base;
        const float* pd = decay  + base;

        f32x4 Cv0 = {0.f,0.f,0.f,0.f}, Cv1 = {0.f,0.f,0.f,0.f};
        f32x4 Ch0 = {0.f,0.f,0.f,0.f}, Ch1 = {0.f,0.f,0.f,0.f};

#pragma unroll
        for (int c = 0; c < 8; ++c) {
            const float4 h0 = *(const float4*)(ph + 32 * c);
            const float4 h1 = *(const float4*)(ph + 32 * c + 4);
            const float4 c0 = *(const float4*)(pc + 32 * c);
            const float4 c1 = *(const float4*)(pc + 32 * c + 4);
            const float4 t0 = *(const float4*)(pt + 32 * c);
            const float4 t1 = *(const float4*)(pt + 32 * c + 4);
            const float4 o0 = *(const float4*)(po + 32 * c);
            const float4 o1 = *(const float4*)(po + 32 * c + 4);
            const float4 d0 = *(const float4*)(pd + 32 * c);
            const float4 d1 = *(const float4*)(pd + 32 * c + 4);

            float4 v0, v1;
            {
                float cs, e2;
                cs = t0.x + (c0.x - t0.x) * __expf(-d0.x * st); e2 = __expf(2.f * cs); v0.x = o0.x * ((e2 - 1.f) / (e2 + 1.f));
                cs = t0.y + (c0.y - t0.y) * __expf(-d0.y * st); e2 = __expf(2.f * cs); v0.y = o0.y * ((e2 - 1.f) / (e2 + 1.f));
                cs = t0.z + (c0.z - t0.z) * __expf(-d0.z * st); e2 = __expf(2.f * cs); v0.z = o0.z * ((e2 - 1.f) / (e2 + 1.f));
                cs = t0.w + (c0.w - t0.w) * __expf(-d0.w * st); e2 = __expf(2.f * cs); v0.w = o0.w * ((e2 - 1.f) / (e2 + 1.f));
                cs = t1.x + (c1.x - t1.x) * __expf(-d1.x * st); e2 = __expf(2.f * cs); v1.x = o1.x * ((e2 - 1.f) / (e2 + 1.f));
                cs = t1.y + (c1.y - t1.y) * __expf(-d1.y * st); e2 = __expf(2.f * cs); v1.y = o1.y * ((e2 - 1.f) / (e2 + 1.f));
                cs = t1.z + (c1.z - t1.z) * __expf(-d1.z * st); e2 = __expf(2.f * cs); v1.z = o1.z * ((e2 - 1.f) / (e2 + 1.f));
                cs = t1.w + (c1.w - t1.w) * __expf(-d1.w * st); e2 = __expf(2.f * cs); v1.w = o1.w * ((e2 - 1.f) / (e2 + 1.f));
            }
            const short8 av = pack_bf16x8(v0, v1);
            const short8 ah = pack_bf16x8(h0, h1);
            Cv0 = __builtin_amdgcn_mfma_f32_16x16x32_bf16(av, w0f[c], Cv0, 0, 0, 0);
            Cv1 = __builtin_amdgcn_mfma_f32_16x16x32_bf16(av, w1f[c], Cv1, 0, 0, 0);
            Ch0 = __builtin_amdgcn_mfma_f32_16x16x32_bf16(ah, w0f[c], Ch0, 0, 0, 0);
            Ch1 = __builtin_amdgcn_mfma_f32_16x16x32_bf16(ah, w1f[c], Ch1, 0, 0, 0);
        }

        // ---- term 2: row = 4g+reg, col = m; sum softplus over 32 cols ----
        float sp[4];
#pragma unroll
        for (int reg = 0; reg < 4; ++reg)
            sp[reg] = softplus_f(Cv0[reg] + b_lo) + softplus_f(Cv1[reg] + b_hi);
#pragma unroll
        for (int mk = 1; mk <= 8; mk <<= 1) {
#pragma unroll
            for (int reg = 0; reg < 4; ++reg) sp[reg] += __shfl_xor(sp[reg], mk, 64);
        }
        float t2 = 0.f;
#pragma unroll
        for (int reg = 0; reg < 4; ++reg) {
            const float cf = __shfl(coef, 4 * g + reg, 64);   // coef of row 4g+reg
            t2 += cf * sp[reg];
        }
        if (m == 0) acc += t2;

        // ---- term 1: hidden-row rr gathered at column e_rr ----
        float kv = 0.f, kb = 0.f;
#pragma unroll
        for (int rr = 0; rr < 16; ++rr) {
            const int   er   = __shfl(e, rr, 64);             // e of row rr (uniform)
            const float cand = (er < 16) ? Ch0[rr & 3] : Ch1[rr & 3];
            const float val  = __shfl(cand, ((rr >> 2) << 4) + (er & 15), 64);
            const float bsel = (er < 16) ? b_lo : b_hi;
            const float be   = __shfl(bsel, er & 15, 64);
            if (lane == rr) { kv = val; kb = be; }
        }
        if (lane < 16 && valid)
            acc -= __logf(softplus_f(kv + kb));
    }

    // wave reduce + block reduce
#pragma unroll
    for (int mk = 1; mk < 64; mk <<= 1) acc += __shfl_xor(acc, mk, 64);
    if (lane == 0) wacc[q] = acc;
    __syncthreads();
    if (tid == 0) partial[blockIdx.x] = wacc[0] + wacc[1] + wacc[2] + wacc[3];
}

// Output: single float32 scalar.
__global__ __launch_bounds__(256) void nhll_finalize(
    const float* __restrict__ partial, float* __restrict__ out)
{
    __shared__ float red[4];
    float s = 0.f;
    for (int i = threadIdx.x; i < NB; i += 256) s += partial[i];
    for (int mk = 1; mk < 64; mk <<= 1) s += __shfl_xor(s, mk, 64);
    if ((threadIdx.x & 63) == 0) red[threadIdx.x >> 6] = s;
    __syncthreads();
    if (threadIdx.x == 0)
        out[0] = red[0] + red[1] + red[2] + red[3];
}

extern "C" void kernel_launch(void* const* d_in, const int* in_sizes, int n_in,
                              void* d_out, int out_size, void* d_ws, size_t ws_size,
                              hipStream_t stream) {
    const int*   events = (const int*)  d_in[0];   // event_seqs  [B,L] int32
    const int*   lens   = (const int*)  d_in[1];   // seqs_length [B]   int32
    const float* ttime  = (const float*)d_in[2];   // total_time  [B]
    const float* hidden = (const float*)d_in[3];   // [L,B,H]
    const float* cell   = (const float*)d_in[4];   // [L,B,H]
    const float* ctarg  = (const float*)d_in[5];   // [L,B,H]
    const float* outp   = (const float*)d_in[6];   // [L,B,H]
    const float* decay  = (const float*)d_in[7];   // [L,B,H]
    const float* simt   = (const float*)d_in[8];   // [L,B]
    const float* W      = (const float*)d_in[9];   // [H,K]
    const float* bias   = (const float*)d_in[10];  // [K]

    float* part = (float*)d_ws;                    // NB floats
    float* out  = (float*)d_out;

    nhll_main<<<NB, 256, 0, stream>>>(events, lens, ttime, hidden, cell, ctarg,
                                      outp, decay, simt, W, bias, part);
    nhll_finalize<<<1, 256, 0, stream>>>(part, out);
}